// Round 5
// baseline (566.930 us; speedup 1.0000x reference)
//
#include <hip/hip_runtime.h>
#include <hip/hip_bf16.h>

#define N_NODES 50000
#define N_EDGES 800000
#define NUM_GRAPHS 512
#define D 64
#define BN_EPS 1e-5f

#define BUK_SHIFT 7
#define BUK_SIZE 128
#define NBUK ((N_NODES + BUK_SIZE - 1) / BUK_SIZE)   // 391
#define CHUNK_A 4096
#define NBLK_A ((N_EDGES + CHUNK_A - 1) / CHUNK_A)   // 196
#define PB 2048

// ---------------- zero: bucket counters + BN accumulators ----------------
__global__ __launch_bounds__(512) void k_zero(int* __restrict__ bcnt,
                                              float* __restrict__ bnacc /*128*/) {
    int t = threadIdx.x;
    for (int j = t; j < NBUK; j += 512) bcnt[j] = 0;
    if (t < 128) bnacc[t] = 0.0f;
}

// ---------------- bucket histogram (LDS-reduced) ----------------
__global__ __launch_bounds__(256) void k_bhist(const int* __restrict__ ei,
                                               int* __restrict__ bcnt) {
    __shared__ int h[NBUK];
    int t = threadIdx.x;
    for (int j = t; j < NBUK; j += 256) h[j] = 0;
    __syncthreads();
    int e0 = blockIdx.x * CHUNK_A;
#pragma unroll
    for (int i = 0; i < CHUNK_A / 256; i++) {
        int e = e0 + i * 256 + t;
        if (e < N_EDGES) atomicAdd(&h[ei[N_EDGES + e] >> BUK_SHIFT], 1);
    }
    __syncthreads();
    for (int j = t; j < NBUK; j += 256)
        if (h[j]) atomicAdd(&bcnt[j], h[j]);
}

// ---------------- exclusive scan of 391 bucket counts ----------------
__global__ __launch_bounds__(512) void k_bscan(const int* __restrict__ bcnt,
                                               int* __restrict__ boffs,
                                               int* __restrict__ gcur) {
    __shared__ int sm[512];
    int t = threadIdx.x;
    int v = (t < NBUK) ? bcnt[t] : 0;
    sm[t] = v;
    __syncthreads();
    for (int off = 1; off < 512; off <<= 1) {
        int a = sm[t];
        int u = (t >= off) ? sm[t - off] : 0;
        __syncthreads();
        sm[t] = a + u;
        __syncthreads();
    }
    if (t < NBUK) { int ex = sm[t] - v; boffs[t] = ex; gcur[t] = ex; }
    if (t == 0) boffs[NBUK] = N_EDGES;
}

// ---------------- pass A: bin edges into buckets, packed u32 (row<<16 | src) ----------------
__global__ __launch_bounds__(256) void k_binA(const int* __restrict__ ei,
                                              int* __restrict__ gcur,
                                              unsigned* __restrict__ pairs) {
    __shared__ int cnt[NBUK];
    __shared__ int base[NBUK];
    int t = threadIdx.x;
    for (int j = t; j < NBUK; j += 256) cnt[j] = 0;
    __syncthreads();
    int e0 = blockIdx.x * CHUNK_A;
    unsigned pd[CHUNK_A / 256];   // (d<<16)|s  (both < 2^16)
    int loc[CHUNK_A / 256];
#pragma unroll
    for (int i = 0; i < CHUNK_A / 256; i++) {
        int e = e0 + i * 256 + t;
        pd[i] = 0xFFFFFFFFu;      // sentinel: real pd has (d>>16) <= 49999
        if (e < N_EDGES) {
            unsigned s = (unsigned)ei[e];
            unsigned d = (unsigned)ei[N_EDGES + e];
            pd[i] = (d << 16) | s;
            loc[i] = atomicAdd(&cnt[d >> BUK_SHIFT], 1);
        }
    }
    __syncthreads();
    for (int j = t; j < NBUK; j += 256)
        base[j] = cnt[j] ? atomicAdd(&gcur[j], cnt[j]) : 0;
    __syncthreads();
#pragma unroll
    for (int i = 0; i < CHUNK_A / 256; i++) {
        if (pd[i] != 0xFFFFFFFFu) {
            unsigned d = pd[i] >> 16;
            pairs[base[d >> BUK_SHIFT] + loc[i]] =
                ((d & (BUK_SIZE - 1)) << 16) | (pd[i] & 0xFFFFu);
        }
    }
}

// ---------------- pass B: per-bucket LDS tile accumulate (reorder-fine + gather fused) ----------------
__global__ __launch_bounds__(256) void k_binB(const float* __restrict__ x,
                                              const int* __restrict__ boffs,
                                              const unsigned* __restrict__ pairs,
                                              float* __restrict__ agg) {
    __shared__ float tile[BUK_SIZE * D];   // 32 KB
    __shared__ unsigned pb[PB];            // 8 KB
    int b = blockIdx.x, t = threadIdx.x;
    int n0 = b << BUK_SHIFT;
    int nrows = min(BUK_SIZE, N_NODES - n0);
    float4* t4 = (float4*)tile;
    const float4* x4 = (const float4*)(x + (size_t)n0 * D);
    int nq = nrows * (D / 4);
    for (int j = t; j < BUK_SIZE * (D / 4); j += 256)
        t4[j] = (j < nq) ? x4[j] : make_float4(0.f, 0.f, 0.f, 0.f);
    int e0 = boffs[b], e1 = boffs[b + 1];
    int w = t >> 6, lane = t & 63;
    for (int cb = e0; cb < e1; cb += PB) {
        int m = min(PB, e1 - cb);
        __syncthreads();                    // tile init / previous chunk done
        for (int j = t; j < m; j += 256) pb[j] = pairs[cb + j];
        __syncthreads();
        int j = w;
        for (; j + 28 < m; j += 32) {       // 8-deep: 8 independent row loads in flight
            unsigned p0 = pb[j],      p1 = pb[j + 4],  p2 = pb[j + 8],  p3 = pb[j + 12];
            unsigned p4 = pb[j + 16], p5 = pb[j + 20], p6 = pb[j + 24], p7 = pb[j + 28];
            float v0 = x[(size_t)(p0 & 0xFFFFu) * D + lane];
            float v1 = x[(size_t)(p1 & 0xFFFFu) * D + lane];
            float v2 = x[(size_t)(p2 & 0xFFFFu) * D + lane];
            float v3 = x[(size_t)(p3 & 0xFFFFu) * D + lane];
            float v4 = x[(size_t)(p4 & 0xFFFFu) * D + lane];
            float v5 = x[(size_t)(p5 & 0xFFFFu) * D + lane];
            float v6 = x[(size_t)(p6 & 0xFFFFu) * D + lane];
            float v7 = x[(size_t)(p7 & 0xFFFFu) * D + lane];
            atomicAdd(&tile[(p0 >> 16) * D + lane], v0);
            atomicAdd(&tile[(p1 >> 16) * D + lane], v1);
            atomicAdd(&tile[(p2 >> 16) * D + lane], v2);
            atomicAdd(&tile[(p3 >> 16) * D + lane], v3);
            atomicAdd(&tile[(p4 >> 16) * D + lane], v4);
            atomicAdd(&tile[(p5 >> 16) * D + lane], v5);
            atomicAdd(&tile[(p6 >> 16) * D + lane], v6);
            atomicAdd(&tile[(p7 >> 16) * D + lane], v7);
        }
        for (; j < m; j += 4) {
            unsigned p = pb[j];
            atomicAdd(&tile[(p >> 16) * D + lane], x[(size_t)(p & 0xFFFFu) * D + lane]);
        }
    }
    __syncthreads();
    float4* a4 = (float4*)(agg + (size_t)n0 * D);
    for (int j = t; j < nq; j += 256) a4[j] = t4[j];
}

// ---------------- GEMM1: hT[c][r] = agg[r][:] @ W1[:,c] + b1[c] ----------------
__global__ __launch_bounds__(256) void k_gemm1(const float* __restrict__ agg,
                                               const float* __restrict__ W1,
                                               const float* __restrict__ b1,
                                               float* __restrict__ hT) {
    int r = blockIdx.x * 256 + threadIdx.x;
    if (r >= N_NODES) return;
    float row[D];
#pragma unroll
    for (int k4 = 0; k4 < D / 4; k4++) {
        float4 v = *(const float4*)(agg + (size_t)r * D + k4 * 4);
        row[k4 * 4 + 0] = v.x; row[k4 * 4 + 1] = v.y;
        row[k4 * 4 + 2] = v.z; row[k4 * 4 + 3] = v.w;
    }
    for (int c4 = 0; c4 < D / 4; c4++) {
        float acc[4];
#pragma unroll
        for (int j = 0; j < 4; j++) acc[j] = b1[c4 * 4 + j];
#pragma unroll
        for (int k = 0; k < D; k++) {
#pragma unroll
            for (int j = 0; j < 4; j++)
                acc[j] += row[k] * W1[k * D + c4 * 4 + j];   // wave-uniform -> scalar path
        }
#pragma unroll
        for (int j = 0; j < 4; j++)
            hT[(size_t)(c4 * 4 + j) * N_NODES + r] = acc[j]; // coalesced
    }
}

// ---------------- BN stats ----------------
__global__ __launch_bounds__(256) void k_bnstats(const float* __restrict__ hT,
                                                 float* __restrict__ bnsum,
                                                 float* __restrict__ bnsq) {
    __shared__ float ls[256], lq[256];
    int c = blockIdx.y;
    const float* p = hT + (size_t)c * N_NODES;
    float s = 0.f, q = 0.f;
    for (int i = blockIdx.x * 256 + threadIdx.x; i < N_NODES; i += 256 * gridDim.x) {
        float v = p[i];
        s += v; q += v * v;
    }
    int t = threadIdx.x;
    ls[t] = s; lq[t] = q;
    __syncthreads();
    for (int off = 128; off; off >>= 1) {
        if (t < off) { ls[t] += ls[t + off]; lq[t] += lq[t + off]; }
        __syncthreads();
    }
    if (t == 0) { atomicAdd(&bnsum[c], ls[0]); atomicAdd(&bnsq[c], lq[0]); }
}

// ---------------- BN finalize ----------------
__global__ void k_bnfinal(const float* __restrict__ bnsum, const float* __restrict__ bnsq,
                          const float* __restrict__ gamma, const float* __restrict__ beta,
                          float* __restrict__ bnscale, float* __restrict__ bnshift) {
    int c = threadIdx.x;  // 64
    float mean = bnsum[c] * (1.0f / N_NODES);
    float var  = bnsq[c] * (1.0f / N_NODES) - mean * mean;
    float rstd = rsqrtf(var + BN_EPS);
    float sc = gamma[c] * rstd;
    bnscale[c] = sc;
    bnshift[c] = beta[c] - mean * sc;
}

// ---------------- GEMM2 ----------------
__global__ __launch_bounds__(256) void k_gemm2(const float* __restrict__ hT,
                                               const float* __restrict__ bnscale,
                                               const float* __restrict__ bnshift,
                                               const float* __restrict__ W2,
                                               const float* __restrict__ b2,
                                               float* __restrict__ h2T) {
    int r = blockIdx.x * 256 + threadIdx.x;
    if (r >= N_NODES) return;
    float row[D];
#pragma unroll
    for (int k = 0; k < D; k++) {
        float v = hT[(size_t)k * N_NODES + r];
        row[k] = fmaxf(v * bnscale[k] + bnshift[k], 0.0f);
    }
    for (int c4 = 0; c4 < D / 4; c4++) {
        float acc[4];
#pragma unroll
        for (int j = 0; j < 4; j++) acc[j] = b2[c4 * 4 + j];
#pragma unroll
        for (int k = 0; k < D; k++) {
#pragma unroll
            for (int j = 0; j < 4; j++)
                acc[j] += row[k] * W2[k * D + c4 * 4 + j];
        }
#pragma unroll
        for (int j = 0; j < 4; j++)
            h2T[(size_t)(c4 * 4 + j) * N_NODES + r] = fmaxf(acc[j], 0.0f);
    }
}

// ---------------- pooling ----------------
__device__ __forceinline__ int lower_bound(const int* __restrict__ b, int v) {
    int lo = 0, hi = N_NODES;
    while (lo < hi) {
        int m = (lo + hi) >> 1;
        if (b[m] < v) lo = m + 1; else hi = m;
    }
    return lo;
}

__global__ __launch_bounds__(64) void k_pool(const float* __restrict__ h2T,
                                             const int* __restrict__ batch,
                                             float* __restrict__ g) {
    int gi = blockIdx.x;
    int c = threadIdx.x;
    int s0 = lower_bound(batch, gi);
    int s1 = lower_bound(batch, gi + 1);
    const float* p = h2T + (size_t)c * N_NODES;
    float sm = 0.0f, mx = 0.0f;   // post-ReLU >= 0
    for (int n = s0; n < s1; n++) {
        float v = p[n];
        sm += v;
        mx = fmaxf(mx, v);
    }
    g[gi * 128 + c] = sm;
    g[gi * 128 + 64 + c] = mx;
}

// ---------------- head ----------------
__global__ __launch_bounds__(128) void k_head(const float* __restrict__ g,
                                              const float* __restrict__ Wl1,
                                              const float* __restrict__ bl1,
                                              const float* __restrict__ Wl2,
                                              const float* __restrict__ bl2,
                                              float* __restrict__ out) {
    __shared__ float gv[128];
    __shared__ float red[2];
    int gi = blockIdx.x;
    int t = threadIdx.x;
    gv[t] = g[gi * 128 + t];
    __syncthreads();
    float acc = bl1[t];
#pragma unroll
    for (int k = 0; k < 128; k++)
        acc += gv[k] * Wl1[k * 128 + t];
    acc = fmaxf(acc, 0.0f);
    float part = acc * Wl2[t];
    for (int off = 32; off; off >>= 1) part += __shfl_down(part, off);
    if ((t & 63) == 0) red[t >> 6] = part;
    __syncthreads();
    if (t == 0) {
        float logit = red[0] + red[1] + bl2[0];
        out[gi] = 1.0f / (1.0f + expf(-logit));
        out[NUM_GRAPHS + gi] = logit;
    }
}

extern "C" void kernel_launch(void* const* d_in, const int* in_sizes, int n_in,
                              void* d_out, int out_size, void* d_ws, size_t ws_size,
                              hipStream_t stream) {
    const float* x     = (const float*)d_in[0];
    const int*   ei    = (const int*)d_in[1];
    const int*   batch = (const int*)d_in[2];
    const float* W1    = (const float*)d_in[3];
    const float* b1    = (const float*)d_in[4];
    const float* gamma = (const float*)d_in[5];
    const float* beta  = (const float*)d_in[6];
    const float* W2    = (const float*)d_in[7];
    const float* b2    = (const float*)d_in[8];
    const float* Wl1   = (const float*)d_in[9];
    const float* bl1   = (const float*)d_in[10];
    const float* Wl2   = (const float*)d_in[11];
    const float* bl2   = (const float*)d_in[12];
    float* out = (float*)d_out;

    float* ws = (float*)d_ws;
    float* agg    = ws;                         // [N][64]
    float* hT     = agg + (size_t)N_NODES * D;  // [64][N]
    float* gbuf   = hT + (size_t)N_NODES * D;   // [512][128]
    float* bnsum  = gbuf + NUM_GRAPHS * 128;    // 64
    float* bnsq   = bnsum + 64;                 // 64
    float* bnscale= bnsq + 64;                  // 64
    float* bnshift= bnscale + 64;               // 64
    int*   bcnt   = (int*)(bnshift + 64);       // [NBUK]
    int*   boffs  = bcnt + NBUK;                // [NBUK+1]
    int*   gcur   = boffs + NBUK + 1;           // [NBUK]
    unsigned* pairs = (unsigned*)(gcur + NBUK); // [E]
    float* h2T    = agg;                        // alias: agg dead after gemm1

    k_zero <<<1, 512, 0, stream>>>(bcnt, bnsum);
    k_bhist<<<NBLK_A, 256, 0, stream>>>(ei, bcnt);
    k_bscan<<<1, 512, 0, stream>>>(bcnt, boffs, gcur);
    k_binA <<<NBLK_A, 256, 0, stream>>>(ei, gcur, pairs);
    k_binB <<<NBUK, 256, 0, stream>>>(x, boffs, pairs, agg);
    k_gemm1<<<(N_NODES + 255) / 256, 256, 0, stream>>>(agg, W1, b1, hT);
    k_bnstats<<<dim3(8, 64), 256, 0, stream>>>(hT, bnsum, bnsq);
    k_bnfinal<<<1, 64, 0, stream>>>(bnsum, bnsq, gamma, beta, bnscale, bnshift);
    k_gemm2<<<(N_NODES + 255) / 256, 256, 0, stream>>>(hT, bnscale, bnshift, W2, b2, h2T);
    k_pool <<<NUM_GRAPHS, 64, 0, stream>>>(h2T, batch, gbuf);
    k_head <<<NUM_GRAPHS, 128, 0, stream>>>(gbuf, Wl1, bl1, Wl2, bl2, out);
}

// Round 8
// 253.763 us; speedup vs baseline: 2.2341x; 2.2341x over previous
//
#include <hip/hip_runtime.h>
#include <hip/hip_bf16.h>

#define N_NODES 50000
#define N_EDGES 800000
#define NUM_GRAPHS 512
#define D 64
#define BN_EPS 1e-5f

#define BUK_SHIFT 7
#define BUK_SIZE 128
#define NBUK ((N_NODES + BUK_SIZE - 1) / BUK_SIZE)   // 391
#define CHUNK_A 4096
#define NBLK_A ((N_EDGES + CHUNK_A - 1) / CHUNK_A)   // 196

// ---------------- zero: bucket counters + BN accumulators + offs tail ----------------
__global__ __launch_bounds__(512) void k_zero(int* __restrict__ bcnt,
                                              float* __restrict__ bnacc /*128*/,
                                              int* __restrict__ offs) {
    int t = threadIdx.x;
    for (int j = t; j < NBUK; j += 512) bcnt[j] = 0;
    if (t < 128) bnacc[t] = 0.0f;
    if (t == 0) offs[N_NODES] = N_EDGES;
}

// ---------------- bucket histogram (LDS-reduced) ----------------
__global__ __launch_bounds__(256) void k_bhist(const int* __restrict__ ei,
                                               int* __restrict__ bcnt) {
    __shared__ int h[NBUK];
    int t = threadIdx.x;
    for (int j = t; j < NBUK; j += 256) h[j] = 0;
    __syncthreads();
    int e0 = blockIdx.x * CHUNK_A;
#pragma unroll
    for (int i = 0; i < CHUNK_A / 256; i++) {
        int e = e0 + i * 256 + t;
        if (e < N_EDGES) atomicAdd(&h[ei[N_EDGES + e] >> BUK_SHIFT], 1);
    }
    __syncthreads();
    for (int j = t; j < NBUK; j += 256)
        if (h[j]) atomicAdd(&bcnt[j], h[j]);
}

// ---------------- exclusive scan of 391 bucket counts ----------------
__global__ __launch_bounds__(512) void k_bscan(const int* __restrict__ bcnt,
                                               int* __restrict__ boffs,
                                               int* __restrict__ gcur) {
    __shared__ int sm[512];
    int t = threadIdx.x;
    int v = (t < NBUK) ? bcnt[t] : 0;
    sm[t] = v;
    __syncthreads();
    for (int off = 1; off < 512; off <<= 1) {
        int a = sm[t];
        int u = (t >= off) ? sm[t - off] : 0;
        __syncthreads();
        sm[t] = a + u;
        __syncthreads();
    }
    if (t < NBUK) { int ex = sm[t] - v; boffs[t] = ex; gcur[t] = ex; }
    if (t == 0) boffs[NBUK] = N_EDGES;
}

// ---------------- pass A: bin edges into buckets, packed u32 (row<<16 | src) ----------------
__global__ __launch_bounds__(256) void k_binA(const int* __restrict__ ei,
                                              int* __restrict__ gcur,
                                              unsigned* __restrict__ pairs) {
    __shared__ int cnt[NBUK];
    __shared__ int base[NBUK];
    int t = threadIdx.x;
    for (int j = t; j < NBUK; j += 256) cnt[j] = 0;
    __syncthreads();
    int e0 = blockIdx.x * CHUNK_A;
    unsigned pd[CHUNK_A / 256];   // (d<<16)|s  (both < 2^16)
    int loc[CHUNK_A / 256];
#pragma unroll
    for (int i = 0; i < CHUNK_A / 256; i++) {
        int e = e0 + i * 256 + t;
        pd[i] = 0xFFFFFFFFu;      // sentinel: real pd has (d>>16) <= 49999
        if (e < N_EDGES) {
            unsigned s = (unsigned)ei[e];
            unsigned d = (unsigned)ei[N_EDGES + e];
            pd[i] = (d << 16) | s;
            loc[i] = atomicAdd(&cnt[d >> BUK_SHIFT], 1);
        }
    }
    __syncthreads();
    for (int j = t; j < NBUK; j += 256)
        base[j] = cnt[j] ? atomicAdd(&gcur[j], cnt[j]) : 0;
    __syncthreads();
#pragma unroll
    for (int i = 0; i < CHUNK_A / 256; i++) {
        if (pd[i] != 0xFFFFFFFFu) {
            unsigned d = pd[i] >> 16;
            pairs[base[d >> BUK_SHIFT] + loc[i]] =
                ((d & (BUK_SIZE - 1)) << 16) | (pd[i] & 0xFFFFu);
        }
    }
}

// ---------------- in-bucket counting sort -> CSR esrc + per-node offs ----------------
// One block per bucket. Writes land in the bucket's contiguous esrc window
// (~8 KB) from one CU -> dirty L2 sectors fill fully, ~1x write amplification.
__global__ __launch_bounds__(256) void k_sort(const unsigned* __restrict__ pairs,
                                              const int* __restrict__ boffs,
                                              int* __restrict__ offs,
                                              int* __restrict__ esrc) {
    __shared__ int cnt[BUK_SIZE];
    __shared__ int sm[BUK_SIZE];
    __shared__ int cur[BUK_SIZE];
    int b = blockIdx.x, t = threadIdx.x;
    int n0 = b << BUK_SHIFT;
    int nrows = min(BUK_SIZE, N_NODES - n0);
    int e0 = boffs[b], e1 = boffs[b + 1];
    int m = e1 - e0;
    if (t < BUK_SIZE) cnt[t] = 0;
    __syncthreads();
    for (int j = t; j < m; j += 256)
        atomicAdd(&cnt[pairs[e0 + j] >> 16], 1);
    __syncthreads();
    if (t < BUK_SIZE) sm[t] = cnt[t];
    __syncthreads();
    for (int off = 1; off < BUK_SIZE; off <<= 1) {   // inclusive scan, 128 wide
        int v = 0, u = 0;
        if (t < BUK_SIZE) { v = sm[t]; u = (t >= off) ? sm[t - off] : 0; }
        __syncthreads();
        if (t < BUK_SIZE) sm[t] = v + u;
        __syncthreads();
    }
    if (t < BUK_SIZE) {
        int ex = sm[t] - cnt[t];                      // exclusive
        cur[t] = ex;
        if (t < nrows) offs[n0 + t] = e0 + ex;        // offs[n0+128] = next bucket's e0
    }
    __syncthreads();
    for (int j = t; j < m; j += 256) {
        unsigned p = pairs[e0 + j];
        int pos = atomicAdd(&cur[p >> 16], 1);
        esrc[e0 + pos] = (int)(p & 0xFFFFu);
    }
}

// ---------------- gather-sum: agg[n] = x[n] + sum_{e: dst=n} x[src_e] ----------------
__global__ __launch_bounds__(256) void k_gather(const float* __restrict__ x,
                                                const int* __restrict__ offs,
                                                const int* __restrict__ esrc,
                                                float* __restrict__ agg) {
    int wid = (blockIdx.x * 256 + threadIdx.x) >> 6;  // wave id = node id
    int c = threadIdx.x & 63;                          // lane = feature
    if (wid >= N_NODES) return;
    int base = offs[wid];
    int end = offs[wid + 1];
    float acc = x[(size_t)wid * D + c];
    int i = base;
    for (; i + 3 < end; i += 4) {
        int s0 = esrc[i], s1 = esrc[i + 1], s2 = esrc[i + 2], s3 = esrc[i + 3];
        float v0 = x[(size_t)s0 * D + c];
        float v1 = x[(size_t)s1 * D + c];
        float v2 = x[(size_t)s2 * D + c];
        float v3 = x[(size_t)s3 * D + c];
        acc += v0; acc += v1; acc += v2; acc += v3;
    }
    for (; i < end; i++) acc += x[(size_t)esrc[i] * D + c];
    agg[(size_t)wid * D + c] = acc;                    // coalesced
}

// ---------------- GEMM1: hT[c][r] = agg[r][:] @ W1[:,c] + b1[c] ----------------
__global__ __launch_bounds__(256) void k_gemm1(const float* __restrict__ agg,
                                               const float* __restrict__ W1,
                                               const float* __restrict__ b1,
                                               float* __restrict__ hT) {
    int r = blockIdx.x * 256 + threadIdx.x;
    if (r >= N_NODES) return;
    float row[D];
#pragma unroll
    for (int k4 = 0; k4 < D / 4; k4++) {
        float4 v = *(const float4*)(agg + (size_t)r * D + k4 * 4);
        row[k4 * 4 + 0] = v.x; row[k4 * 4 + 1] = v.y;
        row[k4 * 4 + 2] = v.z; row[k4 * 4 + 3] = v.w;
    }
    for (int c4 = 0; c4 < D / 4; c4++) {
        float acc[4];
#pragma unroll
        for (int j = 0; j < 4; j++) acc[j] = b1[c4 * 4 + j];
#pragma unroll
        for (int k = 0; k < D; k++) {
#pragma unroll
            for (int j = 0; j < 4; j++)
                acc[j] += row[k] * W1[k * D + c4 * 4 + j];   // wave-uniform -> scalar path
        }
#pragma unroll
        for (int j = 0; j < 4; j++)
            hT[(size_t)(c4 * 4 + j) * N_NODES + r] = acc[j]; // coalesced
    }
}

// ---------------- BN stats ----------------
__global__ __launch_bounds__(256) void k_bnstats(const float* __restrict__ hT,
                                                 float* __restrict__ bnsum,
                                                 float* __restrict__ bnsq) {
    __shared__ float ls[256], lq[256];
    int c = blockIdx.y;
    const float* p = hT + (size_t)c * N_NODES;
    float s = 0.f, q = 0.f;
    for (int i = blockIdx.x * 256 + threadIdx.x; i < N_NODES; i += 256 * gridDim.x) {
        float v = p[i];
        s += v; q += v * v;
    }
    int t = threadIdx.x;
    ls[t] = s; lq[t] = q;
    __syncthreads();
    for (int off = 128; off; off >>= 1) {
        if (t < off) { ls[t] += ls[t + off]; lq[t] += lq[t + off]; }
        __syncthreads();
    }
    if (t == 0) { atomicAdd(&bnsum[c], ls[0]); atomicAdd(&bnsq[c], lq[0]); }
}

// ---------------- BN finalize ----------------
__global__ void k_bnfinal(const float* __restrict__ bnsum, const float* __restrict__ bnsq,
                          const float* __restrict__ gamma, const float* __restrict__ beta,
                          float* __restrict__ bnscale, float* __restrict__ bnshift) {
    int c = threadIdx.x;  // 64
    float mean = bnsum[c] * (1.0f / N_NODES);
    float var  = bnsq[c] * (1.0f / N_NODES) - mean * mean;
    float rstd = rsqrtf(var + BN_EPS);
    float sc = gamma[c] * rstd;
    bnscale[c] = sc;
    bnshift[c] = beta[c] - mean * sc;
}

// ---------------- GEMM2 ----------------
__global__ __launch_bounds__(256) void k_gemm2(const float* __restrict__ hT,
                                               const float* __restrict__ bnscale,
                                               const float* __restrict__ bnshift,
                                               const float* __restrict__ W2,
                                               const float* __restrict__ b2,
                                               float* __restrict__ h2T) {
    int r = blockIdx.x * 256 + threadIdx.x;
    if (r >= N_NODES) return;
    float row[D];
#pragma unroll
    for (int k = 0; k < D; k++) {
        float v = hT[(size_t)k * N_NODES + r];
        row[k] = fmaxf(v * bnscale[k] + bnshift[k], 0.0f);
    }
    for (int c4 = 0; c4 < D / 4; c4++) {
        float acc[4];
#pragma unroll
        for (int j = 0; j < 4; j++) acc[j] = b2[c4 * 4 + j];
#pragma unroll
        for (int k = 0; k < D; k++) {
#pragma unroll
            for (int j = 0; j < 4; j++)
                acc[j] += row[k] * W2[k * D + c4 * 4 + j];
        }
#pragma unroll
        for (int j = 0; j < 4; j++)
            h2T[(size_t)(c4 * 4 + j) * N_NODES + r] = fmaxf(acc[j], 0.0f);
    }
}

// ---------------- pooling ----------------
__device__ __forceinline__ int lower_bound(const int* __restrict__ b, int v) {
    int lo = 0, hi = N_NODES;
    while (lo < hi) {
        int m = (lo + hi) >> 1;
        if (b[m] < v) lo = m + 1; else hi = m;
    }
    return lo;
}

__global__ __launch_bounds__(64) void k_pool(const float* __restrict__ h2T,
                                             const int* __restrict__ batch,
                                             float* __restrict__ g) {
    int gi = blockIdx.x;
    int c = threadIdx.x;
    int s0 = lower_bound(batch, gi);
    int s1 = lower_bound(batch, gi + 1);
    const float* p = h2T + (size_t)c * N_NODES;
    float sm = 0.0f, mx = 0.0f;   // post-ReLU >= 0
    for (int n = s0; n < s1; n++) {
        float v = p[n];
        sm += v;
        mx = fmaxf(mx, v);
    }
    g[gi * 128 + c] = sm;
    g[gi * 128 + 64 + c] = mx;
}

// ---------------- head ----------------
__global__ __launch_bounds__(128) void k_head(const float* __restrict__ g,
                                              const float* __restrict__ Wl1,
                                              const float* __restrict__ bl1,
                                              const float* __restrict__ Wl2,
                                              const float* __restrict__ bl2,
                                              float* __restrict__ out) {
    __shared__ float gv[128];
    __shared__ float red[2];
    int gi = blockIdx.x;
    int t = threadIdx.x;
    gv[t] = g[gi * 128 + t];
    __syncthreads();
    float acc = bl1[t];
#pragma unroll
    for (int k = 0; k < 128; k++)
        acc += gv[k] * Wl1[k * 128 + t];
    acc = fmaxf(acc, 0.0f);
    float part = acc * Wl2[t];
    for (int off = 32; off; off >>= 1) part += __shfl_down(part, off);
    if ((t & 63) == 0) red[t >> 6] = part;
    __syncthreads();
    if (t == 0) {
        float logit = red[0] + red[1] + bl2[0];
        out[gi] = 1.0f / (1.0f + expf(-logit));
        out[NUM_GRAPHS + gi] = logit;
    }
}

extern "C" void kernel_launch(void* const* d_in, const int* in_sizes, int n_in,
                              void* d_out, int out_size, void* d_ws, size_t ws_size,
                              hipStream_t stream) {
    const float* x     = (const float*)d_in[0];
    const int*   ei    = (const int*)d_in[1];
    const int*   batch = (const int*)d_in[2];
    const float* W1    = (const float*)d_in[3];
    const float* b1    = (const float*)d_in[4];
    const float* gamma = (const float*)d_in[5];
    const float* beta  = (const float*)d_in[6];
    const float* W2    = (const float*)d_in[7];
    const float* b2    = (const float*)d_in[8];
    const float* Wl1   = (const float*)d_in[9];
    const float* bl1   = (const float*)d_in[10];
    const float* Wl2   = (const float*)d_in[11];
    const float* bl2   = (const float*)d_in[12];
    float* out = (float*)d_out;

    float* ws = (float*)d_ws;
    float* agg    = ws;                         // [N][64]
    float* hT     = agg + (size_t)N_NODES * D;  // [64][N]
    float* gbuf   = hT + (size_t)N_NODES * D;   // [512][128]
    float* bnsum  = gbuf + NUM_GRAPHS * 128;    // 64
    float* bnsq   = bnsum + 64;                 // 64
    float* bnscale= bnsq + 64;                  // 64
    float* bnshift= bnscale + 64;               // 64
    int*   bcnt   = (int*)(bnshift + 64);       // [NBUK]
    int*   boffs  = bcnt + NBUK;                // [NBUK+1]
    int*   gcur   = boffs + NBUK + 1;           // [NBUK]
    int*   offs   = gcur + NBUK;                // [N+1]
    int*   esrc   = offs + N_NODES + 1;         // [E]
    unsigned* pairs = (unsigned*)hT;            // alias: hT written first in gemm1,
                                                // pairs dead after k_sort
    float* h2T    = agg;                        // alias: agg dead after gemm1

    k_zero <<<1, 512, 0, stream>>>(bcnt, bnsum, offs);
    k_bhist<<<NBLK_A, 256, 0, stream>>>(ei, bcnt);
    k_bscan<<<1, 512, 0, stream>>>(bcnt, boffs, gcur);
    k_binA <<<NBLK_A, 256, 0, stream>>>(ei, gcur, pairs);
    k_sort <<<NBUK, 256, 0, stream>>>(pairs, boffs, offs, esrc);
    k_gather<<<(N_NODES * 64 + 255) / 256, 256, 0, stream>>>(x, offs, esrc, agg);
    k_gemm1<<<(N_NODES + 255) / 256, 256, 0, stream>>>(agg, W1, b1, hT);
    k_bnstats<<<dim3(8, 64), 256, 0, stream>>>(hT, bnsum, bnsq);
    k_bnfinal<<<1, 64, 0, stream>>>(bnsum, bnsq, gamma, beta, bnscale, bnshift);
    k_gemm2<<<(N_NODES + 255) / 256, 256, 0, stream>>>(hT, bnscale, bnshift, W2, b2, h2T);
    k_pool <<<NUM_GRAPHS, 64, 0, stream>>>(h2T, batch, gbuf);
    k_head <<<NUM_GRAPHS, 128, 0, stream>>>(gbuf, Wl1, bl1, Wl2, bl2, out);
}